// Round 1
// 109.722 us; speedup vs baseline: 1.0443x; 1.0443x over previous
//
#include <hip/hip_runtime.h>

typedef _Float16 f16;
typedef f16 f16x8 __attribute__((ext_vector_type(8)));
typedef f16 f16x4 __attribute__((ext_vector_type(4)));
typedef f16 f16x2 __attribute__((ext_vector_type(2)));
typedef float f32x4 __attribute__((ext_vector_type(4)));

union F8 { uint4 u4; f16x8 v; f16x2 h[4]; f16 e[8]; };

// ---------------------------------------------------------------------------
// Prep (weights only):
//   W1P[u][w][v]  = f16(W1s[u][v][w])   (128 x 128 x 32)
//   W2P[u][w2][v] = f16(W2[u][v][w2])   (128 x 32 x 32)
// ---------------------------------------------------------------------------
__global__ __launch_bounds__(256) void prep_kernel(
    const float* __restrict__ W1s, const float* __restrict__ W2,
    f16* __restrict__ W1P, f16* __restrict__ W2P)
{
    __shared__ f16 T[32 * 36];
    const int b = blockIdx.x, t = threadIdx.x;

    const float* src; f16* dst; int u, w0, W;
    if (b < 512) { u = b >> 2; w0 = (b & 3) * 32; W = 128; src = W1s; dst = W1P; }
    else         { u = b - 512; w0 = 0;           W = 32;  src = W2;  dst = W2P; }
    {
        int v = t >> 3, wq = t & 7;
        float4 f = *(const float4*)(src + (size_t)(u * 32 + v) * W + w0 + wq * 4);
        T[v * 36 + wq * 4 + 0] = (f16)f.x;
        T[v * 36 + wq * 4 + 1] = (f16)f.y;
        T[v * 36 + wq * 4 + 2] = (f16)f.z;
        T[v * 36 + wq * 4 + 3] = (f16)f.w;
    }
    __syncthreads();
    {
        int w = t >> 3, vr = t & 7;
        f16x4 o = { T[(vr * 4 + 0) * 36 + w], T[(vr * 4 + 1) * 36 + w],
                    T[(vr * 4 + 2) * 36 + w], T[(vr * 4 + 3) * 36 + w] };
        *(f16x4*)(dst + (size_t)u * (W * 32) + (size_t)(w0 + w) * 32 + vr * 4) = o;
    }
}

// ---------------------------------------------------------------------------
// Fused: GEMM1 + silu  ->  s_act kept in LDS  ->  GEMM2 + head.
// Block = 32 rows x 128 cols, 512 thr (8 waves).  Grid 256 -> 1 block/CU,
// 8 waves/CU = 2 waves/SIMD (same occupancy as the old 2-kernel pipeline).
// Phase 1: wave wv owns 16-col strip c0 = wv*16 (identical per-wave loop to
//          the old gemm1), epilogue writes silu(f16) into sact_lds.
// Phase 2: wave wv owns u-range [wv*16, wv*16+16), 2x16 col tiles of W2P;
//          8-way LDS reduction; fused 32x32 head.
// All register arrays constant-indexed (full unroll) -> nothing in scratch.
// ---------------------------------------------------------------------------
__global__ __launch_bounds__(512, 2) void fused_kernel(
    const float* __restrict__ node_vec, const float* __restrict__ attr,
    const f16* __restrict__ W1P, const float* __restrict__ b1s,
    const f16* __restrict__ W2P, const float* __restrict__ b2,
    const float* __restrict__ W3, const float* __restrict__ b3,
    const float* __restrict__ W4, const float* __restrict__ b4,
    float* __restrict__ out)
{
    __shared__ alignas(16) f16   s_lds[32 * 136];     // input s tile (f16)
    __shared__ alignas(16) f16   sact_lds[32 * 136];  // silu(GEMM1) tile
    __shared__ alignas(16) float red[8][32 * 36];     // 8-wave u-reduction
    __shared__ alignas(16) float W3_lds[32 * 36];
    __shared__ alignas(16) float h_lds[32 * 36];

    const int t  = threadIdx.x;
    const int n0 = blockIdx.x * 32;
    const int wv = t >> 6, l = t & 63, lr = l & 15, q = l >> 4;
    const int c0 = wv * 16;          // phase-1 col strip
    const int u0 = wv * 16;          // phase-2 u range

    // ---- stage s tile: 32 rows x 128 cols, f32 -> f16 ----
    #pragma unroll
    for (int i = 0; i < 2; ++i) {
        int idx = t + 512 * i;
        int r = idx >> 5, c4 = idx & 31;
        float4 f = *(const float4*)(node_vec + (size_t)(n0 + r) * 480 + c4 * 4);
        f16x4 o = { (f16)f.x, (f16)f.y, (f16)f.z, (f16)f.w };
        *(f16x4*)(s_lds + r * 136 + c4 * 4) = o;
    }
    // ---- stage W3 (32x32, stride 36) ----
    if (t < 256) {
        int i = t >> 3, jj = (t & 7) * 4;
        *(f32x4*)(W3_lds + i * 36 + jj) = *(const f32x4*)(W3 + i * 32 + jj);
    }

    // ---- attr fragments (K-invariant, reused by BOTH phases) ----
    F8 af0, af1;
    #pragma unroll
    for (int kk = 0; kk < 4; ++kk) {
        float2 fa = *(const float2*)(attr + (size_t)(n0 + lr) * 32 + q * 8 + kk * 2);
        float2 fb = *(const float2*)(attr + (size_t)(n0 + 16 + lr) * 32 + q * 8 + kk * 2);
        af0.h[kk] = f16x2{ (f16)fa.x, (f16)fa.y };
        af1.h[kk] = f16x2{ (f16)fb.x, (f16)fb.y };
    }

    // ---- prime phase-1 B ring (depth 8): frag(u) = W1P[u][c0+lr][q*8..+7] ----
    const f16* Bp = W1P + ((size_t)(c0 + lr)) * 32 + q * 8;
    f16x8 B[8];
    #pragma unroll
    for (int j = 0; j < 8; ++j)
        B[j] = *(const f16x8*)(Bp + (size_t)j * 4096);

    __syncthreads();

    // ======================= phase 1: GEMM1 =======================
    f32x4 acc0 = {0.f, 0.f, 0.f, 0.f}, acc1 = {0.f, 0.f, 0.f, 0.f};

    F8 s8[2][2];   // [buf][row-tile] — constant indices only
    s8[0][0].v = *(const f16x8*)(s_lds + lr * 136);
    s8[0][1].v = *(const f16x8*)(s_lds + (16 + lr) * 136);

    #pragma unroll
    for (int uo = 0; uo < 16; ++uo) {
        const int cur = uo & 1, nxt = cur ^ 1;
        const int uon = (uo + 1 < 16) ? uo + 1 : 15;
        s8[nxt][0].v = *(const f16x8*)(s_lds + lr * 136 + uon * 8);
        s8[nxt][1].v = *(const f16x8*)(s_lds + (16 + lr) * 136 + uon * 8);
        #pragma unroll
        for (int j = 0; j < 8; ++j) {
            const int u = uo * 8 + j;
            f16x8 bf = B[j];
            if (u + 8 < 128)   // compile-time: skip dead tail reloads
                B[j] = *(const f16x8*)(Bp + (size_t)(u + 8) * 4096);
            f16 sv0 = s8[cur][0].e[j];
            f16 sv1 = s8[cur][1].e[j];
            f16x2 sb0 = { sv0, sv0 }, sb1 = { sv1, sv1 };
            F8 a0, a1;
            #pragma unroll
            for (int kk = 0; kk < 4; ++kk) {
                a0.h[kk] = sb0 * af0.h[kk];
                a1.h[kk] = sb1 * af1.h[kk];
            }
            acc0 = __builtin_amdgcn_mfma_f32_16x16x32_f16(a0.v, bf, acc0, 0, 0, 0);
            acc1 = __builtin_amdgcn_mfma_f32_16x16x32_f16(a1.v, bf, acc1, 0, 0, 0);
        }
    }

    // epilogue: scale, bias, silu -> sact_lds (C layout: col=lr, row=q*4+reg)
    {
        const float bv = b1s[c0 + lr];
        #pragma unroll
        for (int reg = 0; reg < 4; ++reg) {
            float v0 = acc0[reg] * 0.015625f + bv;
            float v1 = acc1[reg] * 0.015625f + bv;
            sact_lds[(q * 4 + reg) * 136 + c0 + lr]        = (f16)(v0 / (1.f + __expf(-v0)));
            sact_lds[(16 + q * 4 + reg) * 136 + c0 + lr]   = (f16)(v1 / (1.f + __expf(-v1)));
        }
    }

    // ---- prime phase-2 B rings while waiting for the barrier ----
    const f16* B2p = W2P + ((size_t)u0 * 32 + lr) * 32 + q * 8;
    f16x8 B0[8], B1[8];
    #pragma unroll
    for (int j = 0; j < 8; ++j) {
        B0[j] = *(const f16x8*)(B2p + (size_t)j * 1024);
        B1[j] = *(const f16x8*)(B2p + (size_t)j * 1024 + 512);
    }

    __syncthreads();

    // ======================= phase 2: GEMM2 =======================
    f32x4 acc00 = {0,0,0,0}, acc01 = {0,0,0,0};
    f32x4 acc10 = {0,0,0,0}, acc11 = {0,0,0,0};

    F8 t8[2][2];
    t8[0][0].v = *(const f16x8*)(sact_lds + lr * 136 + u0);
    t8[0][1].v = *(const f16x8*)(sact_lds + (16 + lr) * 136 + u0);

    #pragma unroll
    for (int uo = 0; uo < 2; ++uo) {
        const int cur = uo & 1, nxt = cur ^ 1;
        const int uon = (uo + 1 < 2) ? uo + 1 : 1;
        t8[nxt][0].v = *(const f16x8*)(sact_lds + lr * 136 + u0 + uon * 8);
        t8[nxt][1].v = *(const f16x8*)(sact_lds + (16 + lr) * 136 + u0 + uon * 8);
        #pragma unroll
        for (int j = 0; j < 8; ++j) {
            const int k = uo * 8 + j;
            f16x8 bf0 = B0[j], bf1 = B1[j];
            if (k + 8 < 16) {  // compile-time: only first uo reloads
                B0[j] = *(const f16x8*)(B2p + (size_t)(k + 8) * 1024);
                B1[j] = *(const f16x8*)(B2p + (size_t)(k + 8) * 1024 + 512);
            }
            f16 sv0 = t8[cur][0].e[j];
            f16 sv1 = t8[cur][1].e[j];
            f16x2 sb0 = { sv0, sv0 }, sb1 = { sv1, sv1 };
            F8 a0, a1;
            #pragma unroll
            for (int kk = 0; kk < 4; ++kk) {
                a0.h[kk] = sb0 * af0.h[kk];
                a1.h[kk] = sb1 * af1.h[kk];
            }
            acc00 = __builtin_amdgcn_mfma_f32_16x16x32_f16(a0.v, bf0, acc00, 0, 0, 0);
            acc01 = __builtin_amdgcn_mfma_f32_16x16x32_f16(a0.v, bf1, acc01, 0, 0, 0);
            acc10 = __builtin_amdgcn_mfma_f32_16x16x32_f16(a1.v, bf0, acc10, 0, 0, 0);
            acc11 = __builtin_amdgcn_mfma_f32_16x16x32_f16(a1.v, bf1, acc11, 0, 0, 0);
        }
    }

    // ---- cross-wave u reduction (8 partials) ----
    #pragma unroll
    for (int reg = 0; reg < 4; ++reg) {
        red[wv][(q * 4 + reg) * 36 + lr]           = acc00[reg];
        red[wv][(q * 4 + reg) * 36 + 16 + lr]      = acc01[reg];
        red[wv][(16 + q * 4 + reg) * 36 + lr]      = acc10[reg];
        red[wv][(16 + q * 4 + reg) * 36 + 16 + lr] = acc11[reg];
    }
    __syncthreads();

    // ---- h = sum/64 + b2 -> h_lds ----
    {
        int row = t >> 4, c2 = (t & 15) * 2;
        float s0 = 0.f, s1 = 0.f;
        #pragma unroll
        for (int w = 0; w < 8; ++w) {
            s0 += red[w][row * 36 + c2];
            s1 += red[w][row * 36 + c2 + 1];
        }
        h_lds[row * 36 + c2]     = s0 * 0.015625f + b2[c2];
        h_lds[row * 36 + c2 + 1] = s1 * 0.015625f + b2[c2 + 1];
    }
    __syncthreads();

    // ---- head: 16 threads per node, 2 output-j each ----
    {
        int node = t >> 4, jj = (t & 15) * 2;
        float a0 = 0.f, a1 = 0.f;
        #pragma unroll
        for (int i = 0; i < 32; ++i) {
            float hv = h_lds[node * 36 + i];
            a0 += hv * W3_lds[i * 36 + jj];
            a1 += hv * W3_lds[i * 36 + jj + 1];
        }
        const float inv = 0.17677669529663687f;  // 1/sqrt(32)
        float p = 0.f;
        float aa[2] = { a0, a1 };
        #pragma unroll
        for (int e = 0; e < 2; ++e) {
            float tv = aa[e] * inv + b3[jj + e];
            float g  = tv / (1.f + __expf(-tv));
            p += g * W4[jj + e] * inv;
        }
        p += __shfl_xor(p, 1);
        p += __shfl_xor(p, 2);
        p += __shfl_xor(p, 4);
        p += __shfl_xor(p, 8);
        if ((t & 15) == 0) out[n0 + node] = p + b4[0];
    }
}

// ---------------------------------------------------------------------------
extern "C" void kernel_launch(void* const* d_in, const int* in_sizes, int n_in,
                              void* d_out, int out_size, void* d_ws, size_t ws_size,
                              hipStream_t stream)
{
    const float* node_vec = (const float*)d_in[0];
    const float* attr     = (const float*)d_in[1];
    const float* W1s      = (const float*)d_in[2];
    const float* b1s      = (const float*)d_in[3];
    // d_in[4..7] (W1g,b1g,W1v1,W1v2) are dead code w.r.t. pred_energy
    const float* W2       = (const float*)d_in[8];
    const float* b2       = (const float*)d_in[9];
    const float* W3       = (const float*)d_in[10];
    const float* b3       = (const float*)d_in[11];
    const float* W4       = (const float*)d_in[12];
    const float* b4       = (const float*)d_in[13];
    float* out = (float*)d_out;

    char* ws = (char*)d_ws;
    f16* W1P = (f16*)(ws);                // 128*128*32*2 = 1 MiB
    f16* W2P = (f16*)(ws + (1u << 20));   // 128*32*32*2  = 256 KiB

    prep_kernel<<<640, 256, 0, stream>>>(W1s, W2, W1P, W2P);
    fused_kernel<<<256, 512, 0, stream>>>(node_vec, attr, W1P, b1s,
                                          W2P, b2, W3, b3, W4, b4, out);
}